// Round 6
// baseline (76.112 us; speedup 1.0000x reference)
//
#include <hip/hip_runtime.h>

// Single fused kernel: FFT convolution via N = 2^18 = 64 x 4096 Cooley-Tukey.
//   n = 4096*n1 + n2, k = k1 + 64*k2.
// Phase A : distributed 64-pt column FFT over n1 (+ W_N^{-n2 k1})   -> A1[seq][k1][n2]
// Phase B1: forward 4096-pt row FFT per (seq,k1)                    -> Spec[seq][k1][k2]
// Phase B2: pointwise * 1/N + inverse 4096-pt row FFT (+W_N^{+n2 k1}) in-place rows 0..127
// Phase C : distributed 64-pt inverse column FFT over k1, unpack    -> out
// Grid barriers: monotone counters in d_ws, zeroed via hipMemsetAsync each call.
// 192 blocks x 512 thr, 73.7KB LDS -> all blocks co-resident on 256 CUs (no deadlock).

#define NTOT 262144
#define TLEN 131072
#define PI2_N    2.3968449808418217e-5f   /* 2*pi / 262144 */
#define PI2_4096 1.5339807878856412e-3f   /* 2*pi / 4096   */
#define PI2_64   9.8174770424681039e-2f   /* 2*pi / 64     */
#define LB(i) ((i) + ((i) >> 3))
#define NBLK 192

__device__ __forceinline__ float2 cadd(float2 a, float2 b) { return make_float2(a.x + b.x, a.y + b.y); }
__device__ __forceinline__ float2 csub(float2 a, float2 b) { return make_float2(a.x - b.x, a.y - b.y); }
__device__ __forceinline__ float2 cmul(float2 a, float2 b) {
    return make_float2(a.x * b.x - a.y * b.y, a.x * b.y + a.y * b.x);
}
__device__ __forceinline__ float2 cexp_(float ang) {
    float s, c;
    __sincosf(ang, &s, &c);
    return make_float2(c, s);
}

template<int SIGN>
__device__ __forceinline__ void dft8(float2 x[8]) {
    const float R2 = 0.70710678118654752f;
    float2 t0 = cadd(x[0], x[4]), t1 = csub(x[0], x[4]);
    float2 t2 = cadd(x[2], x[6]), t3 = csub(x[2], x[6]);
    float2 u0 = cadd(x[1], x[5]), u1 = csub(x[1], x[5]);
    float2 u2 = cadd(x[3], x[7]), u3 = csub(x[3], x[7]);
    float2 it3 = (SIGN > 0) ? make_float2(-t3.y, t3.x) : make_float2(t3.y, -t3.x);
    float2 iu3 = (SIGN > 0) ? make_float2(-u3.y, u3.x) : make_float2(u3.y, -u3.x);
    float2 E0 = cadd(t0, t2), E2 = csub(t0, t2);
    float2 E1 = cadd(t1, it3), E3 = csub(t1, it3);
    float2 O0 = cadd(u0, u2), O2 = csub(u0, u2);
    float2 O1 = cadd(u1, iu3), O3 = csub(u1, iu3);
    float2 iO2 = (SIGN > 0) ? make_float2(-O2.y, O2.x) : make_float2(O2.y, -O2.x);
    float2 w1O1 = (SIGN > 0) ? make_float2(R2 * (O1.x - O1.y), R2 * (O1.y + O1.x))
                             : make_float2(R2 * (O1.x + O1.y), R2 * (O1.y - O1.x));
    float2 w3O3 = (SIGN > 0) ? make_float2(R2 * (-O3.x - O3.y), R2 * (O3.x - O3.y))
                             : make_float2(R2 * (O3.y - O3.x), R2 * (-O3.x - O3.y));
    x[0] = cadd(E0, O0);   x[4] = csub(E0, O0);
    x[1] = cadd(E1, w1O1); x[5] = csub(E1, w1O1);
    x[2] = cadd(E2, iO2);  x[6] = csub(E2, iO2);
    x[3] = cadd(E3, w3O3); x[7] = csub(E3, w3O3);
}

// dft8 with x[4..7] == 0 structurally (reads only x[0..3])
template<int SIGN>
__device__ __forceinline__ void dft8z(float2 x[8]) {
    const float R2 = 0.70710678118654752f;
    float2 x0 = x[0], x1 = x[1], x2 = x[2], x3 = x[3];
    float2 rx2 = (SIGN > 0) ? make_float2(-x2.y, x2.x) : make_float2(x2.y, -x2.x);
    float2 rx3 = (SIGN > 0) ? make_float2(-x3.y, x3.x) : make_float2(x3.y, -x3.x);
    float2 E0 = cadd(x0, x2), E2 = csub(x0, x2);
    float2 E1 = cadd(x0, rx2), E3 = csub(x0, rx2);
    float2 O0 = cadd(x1, x3), O2 = csub(x1, x3);
    float2 O1 = cadd(x1, rx3), O3 = csub(x1, rx3);
    float2 iO2 = (SIGN > 0) ? make_float2(-O2.y, O2.x) : make_float2(O2.y, -O2.x);
    float2 w1O1 = (SIGN > 0) ? make_float2(R2 * (O1.x - O1.y), R2 * (O1.y + O1.x))
                             : make_float2(R2 * (O1.x + O1.y), R2 * (O1.y - O1.x));
    float2 w3O3 = (SIGN > 0) ? make_float2(R2 * (-O3.x - O3.y), R2 * (O3.x - O3.y))
                             : make_float2(R2 * (O3.y - O3.x), R2 * (-O3.x - O3.y));
    x[0] = cadd(E0, O0);   x[4] = csub(E0, O0);
    x[1] = cadd(E1, w1O1); x[5] = csub(E1, w1O1);
    x[2] = cadd(E2, iO2);  x[6] = csub(E2, iO2);
    x[3] = cadd(E3, w3O3); x[7] = csub(E3, w3O3);
}

template<int SIGN>
__device__ __forceinline__ void twbase(float2 x[8], int base, float unit) {
#pragma unroll
    for (int i = 1; i < 8; ++i) {
        float ang = unit * (float)(base * i);
        x[i] = cmul(x[i], cexp_((SIGN < 0) ? -ang : ang));
    }
}

// 4096-pt radix-8 Stockham FFT, 512 threads, double-buffered LDS, 3 barriers.
template<int SIGN>
__device__ void fft4096_block(float2 x[8], int t, float2* L0, float2* L1) {
    dft8<SIGN>(x);
    twbase<SIGN>(x, t, PI2_4096);
#pragma unroll
    for (int i = 0; i < 8; ++i) L0[LB(8 * t + i)] = x[i];
    __syncthreads();
    {
        int q = t & 7, p = t >> 3;
#pragma unroll
        for (int i = 0; i < 8; ++i) x[i] = L0[LB(q + 8 * p + 512 * i)];
        dft8<SIGN>(x);
        twbase<SIGN>(x, 8 * p, PI2_4096);
#pragma unroll
        for (int i = 0; i < 8; ++i) L1[LB(q + 64 * p + 8 * i)] = x[i];
    }
    __syncthreads();
    {
        int q = t & 63, p = t >> 6;
#pragma unroll
        for (int i = 0; i < 8; ++i) x[i] = L1[LB(q + 64 * p + 512 * i)];
        dft8<SIGN>(x);
        twbase<SIGN>(x, 64 * p, PI2_4096);
#pragma unroll
        for (int i = 0; i < 8; ++i) L0[LB(q + 512 * p + 64 * i)] = x[i];
    }
    __syncthreads();
#pragma unroll
    for (int i = 0; i < 8; ++i) x[i] = L0[LB(t + 512 * i)];
    dft8<SIGN>(x);
}

// Device-scope grid barrier: monotone counter, zeroed host-side each call.
__device__ __forceinline__ void gbar(unsigned* ctr, unsigned target) {
    __syncthreads();                     // all waves' vmem drained (vmcnt(0) before s_barrier)
    if (threadIdx.x == 0) {
        __hip_atomic_fetch_add(ctr, 1u, __ATOMIC_ACQ_REL, __HIP_MEMORY_SCOPE_AGENT);
        while (__hip_atomic_load(ctr, __ATOMIC_ACQUIRE, __HIP_MEMORY_SCOPE_AGENT) < target)
            __builtin_amdgcn_s_sleep(2);
    }
    __syncthreads();
}

__global__ void __launch_bounds__(512, 2) fused(const float* __restrict__ audio,
                                                const float* __restrict__ rir,
                                                float2* __restrict__ A1,
                                                float2* __restrict__ Spec,
                                                float* __restrict__ out,
                                                unsigned* __restrict__ bar,
                                                int Lout) {
    __shared__ float2 Lsh[9216];          // 73728 B: {L0[4608], L1[4608]} / colA[64][73]
    const int bid = blockIdx.x;
    const int tid = threadIdx.x;
    const int t = tid & 7;                // radix-8 slot
    const int c = tid >> 3;               // column 0..63

    // ---- Phase A: 64-pt column FFT (zero-padded half), 192 blocks ----
    {
        int seq = bid >> 6;
        int n2 = ((bid & 63) << 6) + c;
        float2 g[8];
        if (seq < 2) {
            const float* c0 = audio + (size_t)(2 * seq) * TLEN;
            const float* c1 = c0 + TLEN;
#pragma unroll
            for (int i = 0; i < 4; ++i) {
                int n = ((t + 8 * i) << 12) + n2;          // n1 = t+8i < 32
                g[i] = make_float2(c0[n], c1[n]);
            }
        } else {
#pragma unroll
            for (int i = 0; i < 4; ++i) {
                int n = ((t + 8 * i) << 12) + n2;
                g[i] = make_float2(rir[TLEN - 1 - n], 0.f);
            }
        }
        dft8z<-1>(g);
#pragma unroll
        for (int i = 1; i < 8; ++i)
            g[i] = cmul(g[i], cexp_(-PI2_64 * (float)(t * i)));
        float2* col = Lsh + (size_t)c * 73;
#pragma unroll
        for (int i = 0; i < 8; ++i) col[t + 8 * i] = g[i]; // phys x[t+8i]
        __syncthreads();
#pragma unroll
        for (int i = 0; i < 8; ++i) g[i] = col[8 * t + i]; // phys x[8t+i]
        dft8<-1>(g);
        float2* dst = A1 + ((size_t)seq << 18) + n2;
#pragma unroll
        for (int i = 0; i < 8; ++i) {
            int k1 = 8 * i + t;                            // rev8(8t+i)
            float2 v = g[i];
            if (k1) v = cmul(v, cexp_(-PI2_N * (float)(n2 * k1)));
            dst[(size_t)k1 << 12] = v;
        }
    }
    gbar(bar + 0, NBLK);

    // ---- Phase B1: forward 4096-pt row FFT, 192 rows ----
    {
        float2 x[8];
        const float2* src = A1 + ((size_t)bid << 12);
#pragma unroll
        for (int i = 0; i < 8; ++i) x[i] = src[tid + 512 * i];
        fft4096_block<-1>(x, tid, Lsh, Lsh + 4608);
        float2* dst = Spec + ((size_t)bid << 12) + tid;
#pragma unroll
        for (int i = 0; i < 8; ++i) dst[512 * i] = x[i];
    }
    gbar(bar + 1, NBLK);

    // ---- Phase B2: pointwise + inverse row FFT, in-place rows 0..127 ----
    if (bid < 128) {
        int k1 = bid & 63;
        const float2* sz = Spec + ((size_t)bid << 12);          // row z*64+k1 == bid
        const float2* sr = Spec + ((size_t)(128 + k1) << 12);   // rir row
        float2 x[8], r8[8];
#pragma unroll
        for (int i = 0; i < 8; ++i) x[i] = sz[tid + 512 * i];
#pragma unroll
        for (int i = 0; i < 8; ++i) r8[i] = sr[tid + 512 * i];
        const float invN = 3.814697265625e-6f;                  // 1/262144
#pragma unroll
        for (int i = 0; i < 8; ++i) {
            float2 y = cmul(x[i], r8[i]);
            x[i] = make_float2(y.x * invN, y.y * invN);
        }
        fft4096_block<1>(x, tid, Lsh, Lsh + 4608);
        float2* d = Spec + ((size_t)bid << 12) + tid;           // in-place (block-exclusive row)
        if (k1) {
#pragma unroll
            for (int i = 0; i < 8; ++i)
                d[512 * i] = cmul(x[i], cexp_(PI2_N * (float)((tid + 512 * i) * k1)));
        } else {
#pragma unroll
            for (int i = 0; i < 8; ++i) d[512 * i] = x[i];
        }
    }
    gbar(bar + 2, NBLK);

    // ---- Phase C: 64-pt inverse column FFT over k1 + unpack, 128 tasks ----
    if (bid < 128) {
        int z = bid >> 6;
        int n2 = ((bid & 63) << 6) + c;
        const float2* src = Spec + ((size_t)z << 18) + n2;      // D rows == Spec rows 0..127
        float2 g[8];
#pragma unroll
        for (int i = 0; i < 8; ++i)
            g[i] = src[(size_t)(8 * i + t) << 12];              // input[k1=8i+t] -> phys x[8t+i]
        dft8<1>(g);
#pragma unroll
        for (int i = 1; i < 8; ++i)
            g[i] = cmul(g[i], cexp_(PI2_64 * (float)(t * i)));
        float2* col = Lsh + (size_t)c * 73;
#pragma unroll
        for (int i = 0; i < 8; ++i) col[8 * t + i] = g[i];      // phys x[8t+i]
        __syncthreads();
#pragma unroll
        for (int i = 0; i < 8; ++i) g[i] = col[t + 8 * i];      // phys x[t+8i]
        dft8<1>(g);
        float* o0 = out + (size_t)(2 * z) * Lout;
        float* o1 = o0 + Lout;
#pragma unroll
        for (int i = 0; i < 8; ++i) {
            int n = ((t + 8 * i) << 12) + n2;                   // n1 = t+8i natural
            if (n < Lout) { o0[n] = g[i].x; o1[n] = g[i].y; }
        }
    }
}

extern "C" void kernel_launch(void* const* d_in, const int* in_sizes, int n_in,
                              void* d_out, int out_size, void* d_ws, size_t ws_size,
                              hipStream_t stream) {
    const float* audio = (const float*)d_in[0];   // (1, 4, T) f32
    const float* rir   = (const float*)d_in[1];   // (T,) f32
    float* out = (float*)d_out;                   // (1, 4, 2T-1) f32
    int Lout = out_size / 4;                      // 262143

    float2* A1   = (float2*)d_ws;                 // 3 * 2^18 complex
    float2* Spec = A1 + 3 * NTOT;                 // 3 * 2^18 complex (B2/C reuse rows 0..127)
    unsigned* bar = (unsigned*)((char*)d_ws + (size_t)6 * NTOT * 8);  // 12.58 MB offset

    hipMemsetAsync(bar, 0, 64, stream);           // zero barrier counters every call
    fused<<<NBLK, 512, 0, stream>>>(audio, rir, A1, Spec, out, bar, Lout);
}

// Round 7
// 29.471 us; speedup vs baseline: 2.5826x; 2.5826x over previous
//
#include <hip/hip_runtime.h>

// FFT convolution via N = 2^18 = 64 x 4096 Cooley-Tukey, 4 dispatches.
//   n = 4096*n1 + n2, k = k1 + 64*k2.
// ka : distributed 64-pt column FFT over n1 (+ W_N^{-n2 k1})   -> A1[seq][k1][n2]
//      (8 threads per column, 512-thr blocks; blocks 0..7 also fill W4096 table)
// kbf: forward 4096-pt row FFT per (seq,k1), table twiddles     -> Spec[seq][k1][k2]
// kbi: pointwise * 1/N + inverse 4096-pt row FFT (+W_N^{+n2 k1}) -> D[z][k1][n2]
// kc : distributed 64-pt inverse column FFT over k1, unpack.    -> out
// All global accesses coalesced at >=32B granularity; no grid barriers (R6 lesson:
// agent-scope barriers thrash cross-XCD L2 - FETCH 9.3MB, 75us).

#define NTOT 262144
#define TLEN 131072
#define PI2_N    2.3968449808418217e-5f   /* 2*pi / 262144 */
#define PI2_4096 1.5339807878856412e-3f   /* 2*pi / 4096   */
#define PI2_64   9.8174770424681039e-2f   /* 2*pi / 64     */
#define LB(i) ((i) + ((i) >> 3))          /* LDS pad for row-FFT buffers */

__device__ __forceinline__ float2 cadd(float2 a, float2 b) { return make_float2(a.x + b.x, a.y + b.y); }
__device__ __forceinline__ float2 csub(float2 a, float2 b) { return make_float2(a.x - b.x, a.y - b.y); }
__device__ __forceinline__ float2 cmul(float2 a, float2 b) {
    return make_float2(a.x * b.x - a.y * b.y, a.x * b.y + a.y * b.x);
}
__device__ __forceinline__ float2 cmulc(float2 a, float2 b) {   // a * conj(b)
    return make_float2(a.x * b.x + a.y * b.y, a.y * b.x - a.x * b.y);
}
__device__ __forceinline__ float2 cexp_(float ang) {
    float s, c;
    __sincosf(ang, &s, &c);
    return make_float2(c, s);
}

template<int SIGN>
__device__ __forceinline__ void dft8(float2 x[8]) {
    const float R2 = 0.70710678118654752f;
    float2 t0 = cadd(x[0], x[4]), t1 = csub(x[0], x[4]);
    float2 t2 = cadd(x[2], x[6]), t3 = csub(x[2], x[6]);
    float2 u0 = cadd(x[1], x[5]), u1 = csub(x[1], x[5]);
    float2 u2 = cadd(x[3], x[7]), u3 = csub(x[3], x[7]);
    float2 it3 = (SIGN > 0) ? make_float2(-t3.y, t3.x) : make_float2(t3.y, -t3.x);
    float2 iu3 = (SIGN > 0) ? make_float2(-u3.y, u3.x) : make_float2(u3.y, -u3.x);
    float2 E0 = cadd(t0, t2), E2 = csub(t0, t2);
    float2 E1 = cadd(t1, it3), E3 = csub(t1, it3);
    float2 O0 = cadd(u0, u2), O2 = csub(u0, u2);
    float2 O1 = cadd(u1, iu3), O3 = csub(u1, iu3);
    float2 iO2 = (SIGN > 0) ? make_float2(-O2.y, O2.x) : make_float2(O2.y, -O2.x);
    float2 w1O1 = (SIGN > 0) ? make_float2(R2 * (O1.x - O1.y), R2 * (O1.y + O1.x))
                             : make_float2(R2 * (O1.x + O1.y), R2 * (O1.y - O1.x));
    float2 w3O3 = (SIGN > 0) ? make_float2(R2 * (-O3.x - O3.y), R2 * (O3.x - O3.y))
                             : make_float2(R2 * (O3.y - O3.x), R2 * (-O3.x - O3.y));
    x[0] = cadd(E0, O0);   x[4] = csub(E0, O0);
    x[1] = cadd(E1, w1O1); x[5] = csub(E1, w1O1);
    x[2] = cadd(E2, iO2);  x[6] = csub(E2, iO2);
    x[3] = cadd(E3, w3O3); x[7] = csub(E3, w3O3);
}

// dft8 with x[4..7] == 0 structurally (reads only x[0..3])
template<int SIGN>
__device__ __forceinline__ void dft8z(float2 x[8]) {
    const float R2 = 0.70710678118654752f;
    float2 x0 = x[0], x1 = x[1], x2 = x[2], x3 = x[3];
    float2 rx2 = (SIGN > 0) ? make_float2(-x2.y, x2.x) : make_float2(x2.y, -x2.x);
    float2 rx3 = (SIGN > 0) ? make_float2(-x3.y, x3.x) : make_float2(x3.y, -x3.x);
    float2 E0 = cadd(x0, x2), E2 = csub(x0, x2);
    float2 E1 = cadd(x0, rx2), E3 = csub(x0, rx2);
    float2 O0 = cadd(x1, x3), O2 = csub(x1, x3);
    float2 O1 = cadd(x1, rx3), O3 = csub(x1, rx3);
    float2 iO2 = (SIGN > 0) ? make_float2(-O2.y, O2.x) : make_float2(O2.y, -O2.x);
    float2 w1O1 = (SIGN > 0) ? make_float2(R2 * (O1.x - O1.y), R2 * (O1.y + O1.x))
                             : make_float2(R2 * (O1.x + O1.y), R2 * (O1.y - O1.x));
    float2 w3O3 = (SIGN > 0) ? make_float2(R2 * (-O3.x - O3.y), R2 * (O3.x - O3.y))
                             : make_float2(R2 * (O3.y - O3.x), R2 * (-O3.x - O3.y));
    x[0] = cadd(E0, O0);   x[4] = csub(E0, O0);
    x[1] = cadd(E1, w1O1); x[5] = csub(E1, w1O1);
    x[2] = cadd(E2, iO2);  x[6] = csub(E2, iO2);
    x[3] = cadd(E3, w3O3); x[7] = csub(E3, w3O3);
}

// twiddle by W4096^(base*i) from table (tab[j] = e^{-2pi i j/4096}); conj for inverse.
template<int SIGN>
__device__ __forceinline__ void twtab(float2 x[8], int base, const float2* __restrict__ tab) {
#pragma unroll
    for (int i = 1; i < 8; ++i) {
        float2 w = tab[base * i];                 // base*i < 4096 for all call sites
        x[i] = (SIGN < 0) ? cmul(x[i], w) : cmulc(x[i], w);
    }
}

// 4096-pt radix-8 Stockham FFT, 512 threads, double-buffered LDS, 3 barriers,
// all twiddles from the L1-resident global table.
template<int SIGN>
__device__ void fft4096_block(float2 x[8], int t, float2* L0, float2* L1,
                              const float2* __restrict__ tab) {
    dft8<SIGN>(x);
    twtab<SIGN>(x, t, tab);
#pragma unroll
    for (int i = 0; i < 8; ++i) L0[LB(8 * t + i)] = x[i];
    __syncthreads();
    {
        int q = t & 7, p = t >> 3;
#pragma unroll
        for (int i = 0; i < 8; ++i) x[i] = L0[LB(q + 8 * p + 512 * i)];
        dft8<SIGN>(x);
        twtab<SIGN>(x, 8 * p, tab);
#pragma unroll
        for (int i = 0; i < 8; ++i) L1[LB(q + 64 * p + 8 * i)] = x[i];
    }
    __syncthreads();
    {
        int q = t & 63, p = t >> 6;
#pragma unroll
        for (int i = 0; i < 8; ++i) x[i] = L1[LB(q + 64 * p + 512 * i)];
        dft8<SIGN>(x);
        twtab<SIGN>(x, 64 * p, tab);
#pragma unroll
        for (int i = 0; i < 8; ++i) L0[LB(q + 512 * p + 64 * i)] = x[i];
    }
    __syncthreads();
#pragma unroll
    for (int i = 0; i < 8; ++i) x[i] = L0[LB(t + 512 * i)];
    dft8<SIGN>(x);
}

// ka: 192 blocks x 512. Distributed 64-pt column FFT (8 thr/column, 64 cols/block).
// seq = bid>>6 (0:c0+ic1, 1:c2+ic3, 2:flipped rir). Blocks 0..7 fill W4096 table.
__global__ void __launch_bounds__(512) ka(const float* __restrict__ audio,
                                          const float* __restrict__ rir,
                                          float2* __restrict__ A1,
                                          float2* __restrict__ tab) {
    __shared__ float2 Lsh[64 * 73];
    const int bid = blockIdx.x;
    const int tid = threadIdx.x;
    const int t = tid & 7;                // radix-8 slot
    const int c = tid >> 3;               // column 0..63

    if (bid < 8)                          // fill twiddle table (read by kbf/kbi)
        tab[bid * 512 + tid] = cexp_(-PI2_4096 * (float)(bid * 512 + tid));

    int seq = bid >> 6;
    int n2 = ((bid & 63) << 6) + c;
    float2 g[8];
    if (seq < 2) {
        const float* c0 = audio + (size_t)(2 * seq) * TLEN;
        const float* c1 = c0 + TLEN;
#pragma unroll
        for (int i = 0; i < 4; ++i) {
            int n = ((t + 8 * i) << 12) + n2;          // n1 = t+8i < 32 (nonzero half)
            g[i] = make_float2(c0[n], c1[n]);
        }
    } else {
#pragma unroll
        for (int i = 0; i < 4; ++i) {
            int n = ((t + 8 * i) << 12) + n2;
            g[i] = make_float2(rir[TLEN - 1 - n], 0.f);
        }
    }
    dft8z<-1>(g);
#pragma unroll
    for (int i = 1; i < 8; ++i)
        g[i] = cmul(g[i], cexp_(-PI2_64 * (float)(t * i)));
    float2* col = Lsh + (size_t)c * 73;
#pragma unroll
    for (int i = 0; i < 8; ++i) col[t + 8 * i] = g[i];  // phys x[t+8i]
    __syncthreads();
#pragma unroll
    for (int i = 0; i < 8; ++i) g[i] = col[8 * t + i];  // phys x[8t+i]
    dft8<-1>(g);
    float2* dst = A1 + ((size_t)seq << 18) + n2;
#pragma unroll
    for (int i = 0; i < 8; ++i) {
        int k1 = 8 * i + t;                             // rev8(8t+i)
        float2 v = g[i];
        if (k1) v = cmul(v, cexp_(-PI2_N * (float)(n2 * k1)));
        dst[(size_t)k1 << 12] = v;
    }
}

// kbf: 192 blocks x 512. One forward 4096-FFT per (seq,k1) row.
__global__ void __launch_bounds__(512) kbf(const float2* __restrict__ A1,
                                           float2* __restrict__ Spec,
                                           const float2* __restrict__ tab) {
    int t = threadIdx.x;
    __shared__ float2 L0[4608], L1[4608];
    const float2* src = A1 + ((size_t)blockIdx.x << 12);
    float2 x[8];
#pragma unroll
    for (int i = 0; i < 8; ++i) x[i] = src[t + 512 * i];
    fft4096_block<-1>(x, t, L0, L1, tab);
    float2* dst = Spec + ((size_t)blockIdx.x << 12) + t;
#pragma unroll
    for (int i = 0; i < 8; ++i) dst[512 * i] = x[i];
}

// kbi: 128 blocks x 512. z = bid>>6, k1 = bid&63. Pointwise + inverse FFT + twiddle.
__global__ void __launch_bounds__(512) kbi(const float2* __restrict__ Spec,
                                           float2* __restrict__ D,
                                           const float2* __restrict__ tab) {
    int k1 = blockIdx.x & 63;
    int t = threadIdx.x;
    __shared__ float2 L0[4608], L1[4608];

    const float2* sz = Spec + ((size_t)blockIdx.x << 12);          // row z*64+k1
    const float2* sr = Spec + ((size_t)(128 + k1) << 12);          // rir row
    float2 x[8], r8[8];
#pragma unroll
    for (int i = 0; i < 8; ++i) x[i] = sz[t + 512 * i];
#pragma unroll
    for (int i = 0; i < 8; ++i) r8[i] = sr[t + 512 * i];

    const float invN = 3.814697265625e-6f;  // 1/262144
#pragma unroll
    for (int i = 0; i < 8; ++i) {
        float2 y = cmul(x[i], r8[i]);
        x[i] = make_float2(y.x * invN, y.y * invN);
    }

    fft4096_block<1>(x, t, L0, L1, tab);

    float2* d = D + ((size_t)blockIdx.x << 12) + t;
    if (k1) {
#pragma unroll
        for (int i = 0; i < 8; ++i)
            d[512 * i] = cmul(x[i], cexp_(PI2_N * (float)((t + 512 * i) * k1)));
    } else {
#pragma unroll
        for (int i = 0; i < 8; ++i) d[512 * i] = x[i];
    }
}

// kc: 128 blocks x 512. Distributed 64-pt inverse column FFT over k1 + unpack.
__global__ void __launch_bounds__(512) kc(const float2* __restrict__ D,
                                          float* __restrict__ out, int Lout) {
    __shared__ float2 Lsh[64 * 73];
    const int bid = blockIdx.x;
    const int tid = threadIdx.x;
    const int t = tid & 7;
    const int c = tid >> 3;
    int z = bid >> 6;
    int n2 = ((bid & 63) << 6) + c;

    const float2* src = D + ((size_t)z << 18) + n2;
    float2 g[8];
#pragma unroll
    for (int i = 0; i < 8; ++i)
        g[i] = src[(size_t)(8 * i + t) << 12];          // input[k1=8i+t] -> phys x[8t+i]
    dft8<1>(g);
#pragma unroll
    for (int i = 1; i < 8; ++i)
        g[i] = cmul(g[i], cexp_(PI2_64 * (float)(t * i)));
    float2* col = Lsh + (size_t)c * 73;
#pragma unroll
    for (int i = 0; i < 8; ++i) col[8 * t + i] = g[i];  // phys x[8t+i]
    __syncthreads();
#pragma unroll
    for (int i = 0; i < 8; ++i) g[i] = col[t + 8 * i];  // phys x[t+8i]
    dft8<1>(g);
    float* o0 = out + (size_t)(2 * z) * Lout;
    float* o1 = o0 + Lout;
#pragma unroll
    for (int i = 0; i < 8; ++i) {
        int n = ((t + 8 * i) << 12) + n2;               // n1 = t+8i natural
        if (n < Lout) { o0[n] = g[i].x; o1[n] = g[i].y; }
    }
}

extern "C" void kernel_launch(void* const* d_in, const int* in_sizes, int n_in,
                              void* d_out, int out_size, void* d_ws, size_t ws_size,
                              hipStream_t stream) {
    const float* audio = (const float*)d_in[0];   // (1, 4, T) f32
    const float* rir   = (const float*)d_in[1];   // (T,) f32
    float* out = (float*)d_out;                   // (1, 4, 2T-1) f32
    int Lout = out_size / 4;                      // 262143

    float2* A1   = (float2*)d_ws;                 // 3 * 2^18 complex
    float2* Spec = A1 + 3 * NTOT;                 // 3 * 2^18 complex
    float2* D    = Spec + 3 * NTOT;               // 2 * 2^18 complex
    float2* tab  = D + 2 * NTOT;                  // 4096 complex (32 KB)

    ka <<<192, 512, 0, stream>>>(audio, rir, A1, tab);
    kbf<<<192, 512, 0, stream>>>(A1, Spec, tab);
    kbi<<<128, 512, 0, stream>>>(Spec, D, tab);
    kc <<<128, 512, 0, stream>>>(D, out, Lout);
}